// Round 9
// baseline (96.360 us; speedup 1.0000x reference)
//
#include <hip/hip_runtime.h>
#include <hip/hip_bf16.h>
#include <math.h>

#define EMBED 256
#define HIDDEN 128
#define NBATCH 4096
#define HISTN 50
#define KNEAR 10
#define D4 64
#define ITEMN 50000
#define XSB 272            // Xs row stride in bytes (256 + 16 pad)
#define RBLK (ITEMN / 4)   // 12500 regions blocks

// fp8 scaling: histT holds 64*val, W1s holds 32*W1, Xs holds 1024*X.
#define SH 64.0f
#define SW 32.0f
#define INV_SXSW (1.0f / 32768.0f)
#define INV_SX (1.0f / 1024.0f)

typedef __attribute__((ext_vector_type(4))) float floatx4;
typedef __attribute__((ext_vector_type(2))) float floatx2;
typedef __attribute__((ext_vector_type(2))) __fp16 half2v;

__device__ inline unsigned pkh2(float a, float b) {       // 2 f32 -> packed f16
    union { half2v h; unsigned u; } cv;
    cv.h = __builtin_amdgcn_cvt_pkrtz(a, b);
    return cv.u;
}
__device__ inline float h2f(unsigned short u) {           // f16 -> f32
    union { unsigned short u; __fp16 h; } cv; cv.u = u;
    return (float)cv.h;
}
// pack 4 f32 -> 4 fp8 e4m3
__device__ inline unsigned pk_fp8x4(float a, float b, float c, float d) {
    int v = __builtin_amdgcn_cvt_pk_fp8_f32(a, b, 0, false);
    v = __builtin_amdgcn_cvt_pk_fp8_f32(c, d, v, true);
    return (unsigned)v;
}
// unpack 4 fp8 -> 4 f32
__device__ inline void up_fp8x4(unsigned u, float* f) {
    floatx2 lo = __builtin_amdgcn_cvt_pk_f32_fp8((int)u, false);
    floatx2 hi = __builtin_amdgcn_cvt_pk_f32_fp8((int)u, true);
    f[0] = lo.x; f[1] = lo.y; f[2] = hi.x; f[3] = hi.y;
}

template<int CTRL>
__device__ __forceinline__ float dppf(float x) {
    return __uint_as_float((unsigned)__builtin_amdgcn_update_dpp(
        0, (int)__float_as_uint(x), CTRL, 0xF, 0xF, true));
}
#define DPP_XOR1 0xB1        // quad_perm [1,0,3,2]
#define DPP_XOR2 0x4E        // quad_perm [2,3,0,1]
#define DPP_HMIR 0x141       // row_half_mirror
#define DPP_MIR  0x140       // row_mirror
#define DPP_BC15 0x142       // row_bcast15
#define DPP_BC31 0x143       // row_bcast31

// ---------------------------------------------------------------------------
// prep_eio: EioT[item] = [E_in row (64 f16) | E_out row (64 f16)]  (256 B/row)
// ---------------------------------------------------------------------------
__global__ __launch_bounds__(256) void prep_eio(
    const float* __restrict__ E_in, const float* __restrict__ E_out,
    unsigned short* __restrict__ EioT)
{
    int tid = blockIdx.x * 256 + threadIdx.x;      // < 800000 exactly
    int row = tid >> 4, c = tid & 15;
    const float* src = (c < 8) ? &E_in[(size_t)row * 64 + (c & 7) * 8]
                               : &E_out[(size_t)row * 64 + (c & 7) * 8];
    float4 a = ((const float4*)src)[0];
    float4 b = ((const float4*)src)[1];
    uint4 o;
    o.x = pkh2(a.x, a.y); o.y = pkh2(a.z, a.w);
    o.z = pkh2(b.x, b.y); o.w = pkh2(b.z, b.w);
    *(uint4*)&EioT[(size_t)row * 128 + c * 8] = o;
}

// ---------------------------------------------------------------------------
// regions5 (+ tail prep): per-item attention, one wave per item.
// Score phase: lane l owns kvflat[10l..10l+10) (d = l, kk = reg index 0..9);
// contiguous conflict-free b32 reads + all-VALU DPP full-wave reduction.
// Softmax computed redundantly per-lane from readlane-broadcast scores.
// Tail blocks: E_hist->histT fp8 + W1 fp8 fragments.
// ---------------------------------------------------------------------------
__global__ __launch_bounds__(256) void regions5(
    const int* __restrict__ np,
    const unsigned short* __restrict__ EioT,
    const float* __restrict__ E_hist, const float* __restrict__ W1,
    unsigned char* __restrict__ histT, unsigned char* __restrict__ W1s)
{
    __shared__ __align__(16) unsigned short tiles[4][2][KNEAR * D4];  // 10 KB

    if (blockIdx.x < RBLK) {
        const int wv = threadIdx.x >> 6;
        const int lane = threadIdx.x & 63;
        const int n = blockIdx.x * 4 + wv;          // 50000 = 12500*4
        const int g16 = lane >> 4, c16 = lane & 15;
        const int half = c16 >> 3, colw = c16 & 7;

        // ---- stage 10 combined rows: verbatim b128 copy ----
#pragma unroll
        for (int j = 0; j < 3; ++j) {
            int r = j * 4 + g16;
            if (r < KNEAR) {
                int item = np[n * KNEAR + r];
                uint4 v = *(const uint4*)&EioT[(size_t)item * 128 + c16 * 8];
                *(uint4*)&tiles[wv][half][r * 64 + colw * 8] = v;
            }
        }
        __asm__ volatile("s_waitcnt lgkmcnt(0)" ::: "memory");

        const int par = lane & 1, cp = lane >> 1;

#pragma unroll
        for (int pass = 0; pass < 2; ++pass) {
            // pass0: q = in row0, kv = out -> region_out (histT cols 192..)
            // pass1: q = out row0, kv = in -> region_in  (histT cols 128..)
            const unsigned short* qrow = tiles[wv][pass];
            const unsigned short* kvt = tiles[wv][1 - pass];

            // ---- partial scores: lane l covers d = l, all 10 kk ----
            float qf = h2f(qrow[lane]);
            const unsigned* kv32 = (const unsigned*)kvt;       // dword view
            unsigned e0 = kv32[5 * lane + 0];
            unsigned e1 = kv32[5 * lane + 1];
            unsigned e2 = kv32[5 * lane + 2];
            unsigned e3 = kv32[5 * lane + 3];
            unsigned e4 = kv32[5 * lane + 4];
            float p[10];
            p[0] = qf * h2f((unsigned short)(e0 & 0xffff));
            p[1] = qf * h2f((unsigned short)(e0 >> 16));
            p[2] = qf * h2f((unsigned short)(e1 & 0xffff));
            p[3] = qf * h2f((unsigned short)(e1 >> 16));
            p[4] = qf * h2f((unsigned short)(e2 & 0xffff));
            p[5] = qf * h2f((unsigned short)(e2 >> 16));
            p[6] = qf * h2f((unsigned short)(e3 & 0xffff));
            p[7] = qf * h2f((unsigned short)(e3 >> 16));
            p[8] = qf * h2f((unsigned short)(e4 & 0xffff));
            p[9] = qf * h2f((unsigned short)(e4 >> 16));

            // ---- full-wave sum, all-VALU DPP ladder (result in lane 63) ----
#pragma unroll
            for (int kk = 0; kk < 10; ++kk) {
                float v = p[kk];
                v += dppf<DPP_XOR1>(v);
                v += dppf<DPP_XOR2>(v);
                v += dppf<DPP_HMIR>(v);
                v += dppf<DPP_MIR>(v);     // rows reduced (16-lane groups)
                v += dppf<DPP_BC15>(v);    // rows 1,3 += rows 0,2
                v += dppf<DPP_BC31>(v);    // rows 2-3 += rows 0-1
                p[kk] = v;
            }

            // ---- broadcast + redundant softmax (uniform across lanes) ----
            float sc[10];
#pragma unroll
            for (int kk = 0; kk < 10; ++kk)
                sc[kk] = __uint_as_float(__builtin_amdgcn_readlane(
                             __float_as_uint(p[kk]), 63)) * 0.125f;
            float mv = sc[0];
#pragma unroll
            for (int kk = 1; kk < 10; ++kk) mv = fmaxf(mv, sc[kk]);
            float w[10];
            float s = 0.f;
#pragma unroll
            for (int kk = 0; kk < 10; ++kk) { w[kk] = __expf(sc[kk] - mv); s += w[kk]; }

            // ---- weighted sum; lane pair covers 2 output dims ----
            float oc0 = 0.f, oc1 = 0.f;
#pragma unroll
            for (int q2 = 0; q2 < 5; ++q2) {
                float ws = par ? w[2 * q2 + 1] : w[2 * q2];   // compile-time idx
                unsigned v = *(const unsigned*)&kvt[(2 * q2 + par) * 64 + cp * 2];
                oc0 = fmaf(h2f((unsigned short)(v & 0xffff)), ws, oc0);
                oc1 = fmaf(h2f((unsigned short)(v >> 16)), ws, oc1);
            }
            oc0 += dppf<DPP_XOR1>(oc0);       // combine row parities
            oc1 += dppf<DPP_XOR1>(oc1);
            if (!par) {
                float scl = SH / s;           // fold softmax denom into scale
                unsigned char* dst = histT + (size_t)n * 256
                                     + (pass ? 128 : 192) + cp * 2;
                int v2 = __builtin_amdgcn_cvt_pk_fp8_f32(oc0 * scl, oc1 * scl, 0, false);
                *(unsigned short*)dst = (unsigned short)(v2 & 0xffff);
            }
        }
        return;
    }

    // ---- tail prep ----
    long t = (long)(blockIdx.x - RBLK) * 256 + threadIdx.x;
    if (t < (long)ITEMN * 16) {               // histT hist cols (fp8, x64)
        int row = (int)(t >> 4);
        int c8 = ((int)t & 15) * 8;
        const float4* s = (const float4*)&E_hist[(size_t)row * 128 + c8];
        float4 a = s[0], b = s[1];
        uint2 o;
        o.x = pk_fp8x4(a.x * SH, a.y * SH, a.z * SH, a.w * SH);
        o.y = pk_fp8x4(b.x * SH, b.y * SH, b.z * SH, b.w * SH);
        *(uint2*)&histT[(size_t)row * 256 + c8] = o;
        return;
    }
    t -= (long)ITEMN * 16;
    if (t < 4096) {                           // W1 -> fp8 B-fragments (x32)
        int l = (int)t & 63;
        int f = (int)t >> 6;
        int k = f >> 3, nt = f & 7;
        int row = nt * 16 + (l & 15);
        int col = k * 32 + ((l >> 4) << 3);
        const float* src = W1 + row * EMBED + col;
        uint2 o;
        o.x = pk_fp8x4(src[0] * SW, src[1] * SW, src[2] * SW, src[3] * SW);
        o.y = pk_fp8x4(src[4] * SW, src[5] * SW, src[6] * SW, src[7] * SW);
        *(uint2*)&W1s[(size_t)t * 8] = o;
    }
}

// ---------------------------------------------------------------------------
// score: one block (4 waves) per batch element. fp8 X (LDS) + fp8 W1 MFMA.
// (r7-proven, unchanged)
// ---------------------------------------------------------------------------
__global__ __launch_bounds__(256, 6) void score_kernel(
    const int* __restrict__ history, const int* __restrict__ target,
    const unsigned char* __restrict__ histT,
    const float* __restrict__ E_targ,
    const unsigned char* __restrict__ W1s,
    const float* __restrict__ b1, const float* __restrict__ W2,
    float* __restrict__ out)
{
    __shared__ __align__(16) unsigned char Xs[64][XSB];   // 17.4 KB
    __shared__ float scoreP[4][64];
    __shared__ float rowsumS[64];

    const int t = threadIdx.x;
    const int lane = t & 63;
    const int wv = t >> 6;
    const int b = blockIdx.x;
    const int ti = target[b];
    const int nt0 = wv * 2;
    const int c4 = lane * 4;

    // ---- issue all gathers up front ----
    unsigned uu[13];
    int hrow[13];
#pragma unroll
    for (int j = 0; j < 13; ++j) {
        int h = wv + j * 4;
        hrow[j] = h;
        if (h < HISTN) {
            int item = history[b * HISTN + h];
            uu[j] = *(const unsigned*)&histT[(size_t)item * 256 + c4];
        }
    }

    // tg factors for my 4 columns, pre-multiplied so Xs = 1024*X
    float tgs[4];
    if (c4 < 128) {
        float4 v = *(const float4*)&E_targ[(size_t)ti * 128 + c4];
        tgs[0] = v.x * 16.f; tgs[1] = v.y * 16.f;
        tgs[2] = v.z * 16.f; tgs[3] = v.w * 16.f;
    } else {
        // targ = [E_targ | Rout | Rin]; histT = [E_hist | Rin | Rout]
        int src = (c4 < 192) ? (c4 + 64) : (c4 - 64);
        unsigned u = *(const unsigned*)&histT[(size_t)ti * 256 + src];
        float f[4]; up_fp8x4(u, f);                 // = 64*tg
        tgs[0] = f[0] * 0.25f; tgs[1] = f[1] * 0.25f;
        tgs[2] = f[2] * 0.25f; tgs[3] = f[3] * 0.25f;
    }

    // ---- process + write X (fp8, scaled by 1024) ----
#pragma unroll
    for (int j = 0; j < 13; ++j) {
        if (hrow[j] < HISTN) {
            float f[4]; up_fp8x4(uu[j], f);
            *(unsigned*)&Xs[hrow[j]][c4] =
                pk_fp8x4(f[0] * tgs[0], f[1] * tgs[1], f[2] * tgs[2], f[3] * tgs[3]);
        }
    }
    __syncthreads();

    // ---- GEMM: H1 = X @ W1^T (fp8 MFMA); rowsum via B=ones ----
    floatx4 acc[4][2];
    floatx4 accr = (floatx4){0.f, 0.f, 0.f, 0.f};
#pragma unroll
    for (int m = 0; m < 4; ++m)
#pragma unroll
        for (int n = 0; n < 2; ++n) acc[m][n] = (floatx4){0.f, 0.f, 0.f, 0.f};

    const int ar = lane & 15;
    const int kb8 = (lane >> 4) << 3;
    const long* W1f = (const long*)W1s;
    const long ones = 0x3838383838383838L;          // fp8 e4m3 1.0 x8

#pragma unroll
    for (int k = 0; k < 8; ++k) {
        long a0 = *(const long*)&Xs[ar][k * 32 + kb8];
        long a1 = *(const long*)&Xs[16 + ar][k * 32 + kb8];
        long a2 = *(const long*)&Xs[32 + ar][k * 32 + kb8];
        long a3 = *(const long*)&Xs[48 + ar][k * 32 + kb8];
        long ax = *(const long*)&Xs[wv * 16 + ar][k * 32 + kb8];
        long bq0 = W1f[(k * 8 + nt0) * 64 + lane];
        long bq1 = W1f[(k * 8 + nt0 + 1) * 64 + lane];
        acc[0][0] = __builtin_amdgcn_mfma_f32_16x16x32_fp8_fp8(a0, bq0, acc[0][0], 0, 0, 0);
        acc[0][1] = __builtin_amdgcn_mfma_f32_16x16x32_fp8_fp8(a0, bq1, acc[0][1], 0, 0, 0);
        acc[1][0] = __builtin_amdgcn_mfma_f32_16x16x32_fp8_fp8(a1, bq0, acc[1][0], 0, 0, 0);
        acc[1][1] = __builtin_amdgcn_mfma_f32_16x16x32_fp8_fp8(a1, bq1, acc[1][1], 0, 0, 0);
        acc[2][0] = __builtin_amdgcn_mfma_f32_16x16x32_fp8_fp8(a2, bq0, acc[2][0], 0, 0, 0);
        acc[2][1] = __builtin_amdgcn_mfma_f32_16x16x32_fp8_fp8(a2, bq1, acc[2][1], 0, 0, 0);
        acc[3][0] = __builtin_amdgcn_mfma_f32_16x16x32_fp8_fp8(a3, bq0, acc[3][0], 0, 0, 0);
        acc[3][1] = __builtin_amdgcn_mfma_f32_16x16x32_fp8_fp8(a3, bq1, acc[3][1], 0, 0, 0);
        accr      = __builtin_amdgcn_mfma_f32_16x16x32_fp8_fp8(ax, ones, accr, 0, 0, 0);
    }

    if (ar == 0) {
        int hb = wv * 16 + ((lane >> 4) << 2);
        rowsumS[hb + 0] = accr[0] * INV_SX;
        rowsumS[hb + 1] = accr[1] * INV_SX;
        rowsumS[hb + 2] = accr[2] * INV_SX;
        rowsumS[hb + 3] = accr[3] * INV_SX;
    }

    float w2v[2], b1v[2];
#pragma unroll
    for (int n = 0; n < 2; ++n) {
        int o = (nt0 + n) * 16 + ar;
        w2v[n] = W2[o];
        b1v[n] = b1[o];
    }
#pragma unroll
    for (int m = 0; m < 4; ++m) {
        float p[4] = {0.f, 0.f, 0.f, 0.f};
#pragma unroll
        for (int n = 0; n < 2; ++n)
#pragma unroll
            for (int r = 0; r < 4; ++r)
                p[r] += w2v[n] * fmaxf(acc[m][n][r] * INV_SXSW + b1v[n], 0.f);
#pragma unroll
        for (int r = 0; r < 4; ++r) {
            float v = p[r];
            v += __shfl_xor(v, 1); v += __shfl_xor(v, 2);
            v += __shfl_xor(v, 4); v += __shfl_xor(v, 8);
            if (ar == 0) scoreP[wv][m * 16 + ((lane >> 4) << 2) + r] = v;
        }
    }
    __syncthreads();

    if (wv == 0) {
        float e = 0.f, er = 0.f;
        if (lane < HISTN) {
            int item = history[b * HISTN + lane];
            float sc = scoreP[0][lane] + scoreP[1][lane] + scoreP[2][lane] + scoreP[3][lane];
            e = (item != ti) ? expf(sc) : 0.f;
            er = e * rowsumS[lane];
        }
#pragma unroll
        for (int off = 1; off < 64; off <<= 1) {
            e += __shfl_xor(e, off);
            er += __shfl_xor(er, off);
        }
        if (lane == 0) {
            float pred = er / sqrtf(e);        // denom = (sum e)^0.5
            out[b] = 1.f / (1.f + expf(-pred));
        }
    }
}

extern "C" void kernel_launch(void* const* d_in, const int* in_sizes, int n_in,
                              void* d_out, int out_size, void* d_ws, size_t ws_size,
                              hipStream_t stream) {
    const int* history = (const int*)d_in[0];        // (4096,50)
    const int* target = (const int*)d_in[1];         // (4096,)
    const int* near_pois = (const int*)d_in[2];      // (50000,10)
    // d_in[3] = target_region: unused by reference
    const float* E_in = (const float*)d_in[4];       // (50000,64)
    const float* E_out = (const float*)d_in[5];      // (50000,64)
    const float* E_hist = (const float*)d_in[6];     // (50000,128)
    const float* E_targ = (const float*)d_in[7];     // (50000,128)
    const float* W1 = (const float*)d_in[8];         // (128,256)
    const float* b1 = (const float*)d_in[9];         // (128,)
    const float* W2 = (const float*)d_in[10];        // (1,128)
    float* out = (float*)d_out;                      // (4096,)

    unsigned char* W1s = (unsigned char*)d_ws;                   // 32 KB
    unsigned char* histT = W1s + 32768;                          // 12.8 MB fp8
    unsigned short* EioT = (unsigned short*)(histT + (size_t)ITEMN * 256); // 12.8 MB f16

    prep_eio<<<(ITEMN * 16) / 256, 256, 0, stream>>>(E_in, E_out, EioT);

    const int tailBlocks = (int)(((long)ITEMN * 16 + 4096 + 255) / 256);
    regions5<<<RBLK + tailBlocks, 256, 0, stream>>>(
        near_pois, EioT, E_hist, W1, histT, W1s);

    score_kernel<<<NBATCH, 256, 0, stream>>>(
        history, target, histT, E_targ, W1s, b1, W2, out);
}

// Round 10
// 68.883 us; speedup vs baseline: 1.3989x; 1.3989x over previous
//
#include <hip/hip_runtime.h>
#include <hip/hip_bf16.h>
#include <math.h>

#define EMBED 256
#define HIDDEN 128
#define NBATCH 4096
#define HISTN 50
#define KNEAR 10
#define D4 64
#define ITEMN 50000
#define XSB 272            // Xs row stride in bytes (256 + 16 pad)
#define RBLK (ITEMN / 4)   // 12500 regions blocks

// fp8 scaling: histT holds 64*val, W1s holds 32*W1, Xs holds 1024*X.
#define SH 64.0f
#define SW 32.0f
#define INV_SXSW (1.0f / 32768.0f)
#define INV_SX (1.0f / 1024.0f)

typedef __attribute__((ext_vector_type(4))) float floatx4;
typedef __attribute__((ext_vector_type(2))) float floatx2;
typedef __attribute__((ext_vector_type(2))) __fp16 half2v;

__device__ inline unsigned pkh2(float a, float b) {       // 2 f32 -> packed f16
    union { half2v h; unsigned u; } cv;
    cv.h = __builtin_amdgcn_cvt_pkrtz(a, b);
    return cv.u;
}
__device__ inline float h2f(unsigned short u) {           // f16 -> f32
    union { unsigned short u; __fp16 h; } cv; cv.u = u;
    return (float)cv.h;
}
// pack 4 f32 -> 4 fp8 e4m3
__device__ inline unsigned pk_fp8x4(float a, float b, float c, float d) {
    int v = __builtin_amdgcn_cvt_pk_fp8_f32(a, b, 0, false);
    v = __builtin_amdgcn_cvt_pk_fp8_f32(c, d, v, true);
    return (unsigned)v;
}
// unpack 4 fp8 -> 4 f32
__device__ inline void up_fp8x4(unsigned u, float* f) {
    floatx2 lo = __builtin_amdgcn_cvt_pk_f32_fp8((int)u, false);
    floatx2 hi = __builtin_amdgcn_cvt_pk_f32_fp8((int)u, true);
    f[0] = lo.x; f[1] = lo.y; f[2] = hi.x; f[3] = hi.y;
}

template<int CTRL>
__device__ __forceinline__ float dppf(float x) {
    return __uint_as_float((unsigned)__builtin_amdgcn_update_dpp(
        0, (int)__float_as_uint(x), CTRL, 0xF, 0xF, true));
}
#define DPP_XOR1 0xB1        // quad_perm [1,0,3,2]
#define DPP_XOR2 0x4E        // quad_perm [2,3,0,1]
#define DPP_HMIR 0x141       // row_half_mirror
#define DPP_MIR  0x140       // row_mirror

// ---------------------------------------------------------------------------
// prep_eio: EioT[item] = [E_in row (64 f16) | E_out row (64 f16)]  (256 B/row)
// ---------------------------------------------------------------------------
__global__ __launch_bounds__(256) void prep_eio(
    const float* __restrict__ E_in, const float* __restrict__ E_out,
    unsigned short* __restrict__ EioT)
{
    int tid = blockIdx.x * 256 + threadIdx.x;      // < 800000 exactly
    int row = tid >> 4, c = tid & 15;
    const float* src = (c < 8) ? &E_in[(size_t)row * 64 + (c & 7) * 8]
                               : &E_out[(size_t)row * 64 + (c & 7) * 8];
    float4 a = ((const float4*)src)[0];
    float4 b = ((const float4*)src)[1];
    uint4 o;
    o.x = pkh2(a.x, a.y); o.y = pkh2(a.z, a.w);
    o.z = pkh2(b.x, b.y); o.w = pkh2(b.z, b.w);
    *(uint4*)&EioT[(size_t)row * 128 + c * 8] = o;
}

// ---------------------------------------------------------------------------
// regions6 (+ tail prep): r7's regions3 with ONLY the q.kv score walk changed:
// lane (g8=lane&7, prc=min(lane>>3,4)) accumulates kk-pair (2prc,2prc+1) over
// d in [8g8,8g8+8) via 8 conflict-light ds_read_b32 (dword = both kks) and a
// single b128 q read; 3-DPP exact 8-group reduce; 2-shfl redistribute into
// r7's proven lane-per-kk softmax/wsum (verbatim below).
// Tail blocks: E_hist->histT fp8 + W1 fp8 fragments (unchanged).
// ---------------------------------------------------------------------------
__global__ __launch_bounds__(256) void regions6(
    const int* __restrict__ np,
    const unsigned short* __restrict__ EioT,
    const float* __restrict__ E_hist, const float* __restrict__ W1,
    unsigned char* __restrict__ histT, unsigned char* __restrict__ W1s)
{
    __shared__ __align__(16) unsigned short tiles[4][2][KNEAR * D4];  // 10 KB

    if (blockIdx.x < RBLK) {
        const int wv = threadIdx.x >> 6;
        const int lane = threadIdx.x & 63;
        const int n = blockIdx.x * 4 + wv;          // 50000 = 12500*4
        const int g16 = lane >> 4, c16 = lane & 15;
        const int half = c16 >> 3, colw = c16 & 7;

        // ---- stage 10 combined rows: verbatim b128 copy (r7) ----
#pragma unroll
        for (int j = 0; j < 3; ++j) {
            int r = j * 4 + g16;
            if (r < KNEAR) {
                int item = np[n * KNEAR + r];
                uint4 v = *(const uint4*)&EioT[(size_t)item * 128 + c16 * 8];
                *(uint4*)&tiles[wv][half][r * 64 + colw * 8] = v;
            }
        }
        __asm__ volatile("s_waitcnt lgkmcnt(0)" ::: "memory");

        const int kk = c16;
        const int par = lane & 1, cp = lane >> 1;
        const int g8 = lane & 7;
        const int prc = min(lane >> 3, 4);
        const int srcl = (c16 >> 1) << 3;           // lane holding pair c16>>1

#pragma unroll
        for (int pass = 0; pass < 2; ++pass) {
            // pass0: q = in row0, kv = out -> region_out (histT cols 192..)
            // pass1: q = out row0, kv = in -> region_in  (histT cols 128..)
            const unsigned short* qrow = tiles[wv][pass];
            const unsigned short* kvt = tiles[wv][1 - pass];

            // ---- NEW walk: pair (2prc,2prc+1) over d = 8g8..8g8+7 ----
            float qf[8];
            {
                uint4 qa = *(const uint4*)&qrow[g8 * 8];
                unsigned wd[4] = {qa.x, qa.y, qa.z, qa.w};
#pragma unroll
                for (int m = 0; m < 4; ++m) {
                    qf[2 * m]     = h2f((unsigned short)(wd[m] & 0xffff));
                    qf[2 * m + 1] = h2f((unsigned short)(wd[m] >> 16));
                }
            }
            const unsigned* kv32 = (const unsigned*)kvt;   // dword view
            float p0 = 0.f, p1 = 0.f;
#pragma unroll
            for (int i = 0; i < 8; ++i) {
                // dword index = (10*(8g8+i) + 2prc)/2 = 40g8 + 5i + prc
                unsigned v = kv32[40 * g8 + 5 * i + prc];
                p0 = fmaf(h2f((unsigned short)(v & 0xffff)), qf[i], p0);
                p1 = fmaf(h2f((unsigned short)(v >> 16)), qf[i], p1);
            }
            // exact 8-group sum over g8 (lane bits 0-2), VALU-only
            p0 += dppf<DPP_XOR1>(p0); p0 += dppf<DPP_XOR2>(p0); p0 += dppf<DPP_HMIR>(p0);
            p1 += dppf<DPP_XOR1>(p1); p1 += dppf<DPP_XOR2>(p1); p1 += dppf<DPP_HMIR>(p1);
            // redistribute to lane-per-kk (r7 layout): kk = c16
            float v0 = __shfl(p0, srcl);
            float v1 = __shfl(p1, srcl);
            float sc = ((c16 & 1) ? v1 : v0) * 0.125f;     // / sqrt(64)

            // ---- softmax over 10 keys within each 16-lane group (r7) ----
            float mv = (kk < 10) ? sc : -1e30f;
            mv = fmaxf(mv, dppf<DPP_XOR1>(mv));
            mv = fmaxf(mv, dppf<DPP_XOR2>(mv));
            mv = fmaxf(mv, dppf<DPP_HMIR>(mv));
            mv = fmaxf(mv, dppf<DPP_MIR>(mv));
            float e = (kk < 10) ? __expf(sc - mv) : 0.f;
            float s = e;
            s += dppf<DPP_XOR1>(s);
            s += dppf<DPP_XOR2>(s);
            s += dppf<DPP_HMIR>(s);
            s += dppf<DPP_MIR>(s);
            float w = e / s;

            // ---- weighted sum over keys; lane pair covers 2 dims (r7) ----
            float oc0 = 0.f, oc1 = 0.f;
#pragma unroll
            for (int q2 = 0; q2 < 5; ++q2) {
                float we = __uint_as_float(__builtin_amdgcn_readlane(__float_as_uint(w), 2 * q2));
                float wo = __uint_as_float(__builtin_amdgcn_readlane(__float_as_uint(w), 2 * q2 + 1));
                float ws = par ? wo : we;
                unsigned v = *(const unsigned*)&kvt[(2 * q2 + par) * 64 + cp * 2];
                oc0 = fmaf(h2f((unsigned short)(v & 0xffff)), ws, oc0);
                oc1 = fmaf(h2f((unsigned short)(v >> 16)), ws, oc1);
            }
            oc0 += dppf<DPP_XOR1>(oc0);       // combine row parities
            oc1 += dppf<DPP_XOR1>(oc1);
            if (!par) {
                unsigned char* dst = histT + (size_t)n * 256
                                     + (pass ? 128 : 192) + cp * 2;
                int v2 = __builtin_amdgcn_cvt_pk_fp8_f32(oc0 * SH, oc1 * SH, 0, false);
                *(unsigned short*)dst = (unsigned short)(v2 & 0xffff);
            }
        }
        return;
    }

    // ---- tail prep (r7 verbatim) ----
    long t = (long)(blockIdx.x - RBLK) * 256 + threadIdx.x;
    if (t < (long)ITEMN * 16) {               // histT hist cols (fp8, x64)
        int row = (int)(t >> 4);
        int c8 = ((int)t & 15) * 8;
        const float4* s = (const float4*)&E_hist[(size_t)row * 128 + c8];
        float4 a = s[0], b = s[1];
        uint2 o;
        o.x = pk_fp8x4(a.x * SH, a.y * SH, a.z * SH, a.w * SH);
        o.y = pk_fp8x4(b.x * SH, b.y * SH, b.z * SH, b.w * SH);
        *(uint2*)&histT[(size_t)row * 256 + c8] = o;
        return;
    }
    t -= (long)ITEMN * 16;
    if (t < 4096) {                           // W1 -> fp8 B-fragments (x32)
        int l = (int)t & 63;
        int f = (int)t >> 6;
        int k = f >> 3, nt = f & 7;
        int row = nt * 16 + (l & 15);
        int col = k * 32 + ((l >> 4) << 3);
        const float* src = W1 + row * EMBED + col;
        uint2 o;
        o.x = pk_fp8x4(src[0] * SW, src[1] * SW, src[2] * SW, src[3] * SW);
        o.y = pk_fp8x4(src[4] * SW, src[5] * SW, src[6] * SW, src[7] * SW);
        *(uint2*)&W1s[(size_t)t * 8] = o;
    }
}

// ---------------------------------------------------------------------------
// score: one block (4 waves) per batch element. fp8 X (LDS) + fp8 W1 MFMA.
// (r7-proven, unchanged)
// ---------------------------------------------------------------------------
__global__ __launch_bounds__(256, 6) void score_kernel(
    const int* __restrict__ history, const int* __restrict__ target,
    const unsigned char* __restrict__ histT,
    const float* __restrict__ E_targ,
    const unsigned char* __restrict__ W1s,
    const float* __restrict__ b1, const float* __restrict__ W2,
    float* __restrict__ out)
{
    __shared__ __align__(16) unsigned char Xs[64][XSB];   // 17.4 KB
    __shared__ float scoreP[4][64];
    __shared__ float rowsumS[64];

    const int t = threadIdx.x;
    const int lane = t & 63;
    const int wv = t >> 6;
    const int b = blockIdx.x;
    const int ti = target[b];
    const int nt0 = wv * 2;
    const int c4 = lane * 4;

    // ---- issue all gathers up front ----
    unsigned uu[13];
    int hrow[13];
#pragma unroll
    for (int j = 0; j < 13; ++j) {
        int h = wv + j * 4;
        hrow[j] = h;
        if (h < HISTN) {
            int item = history[b * HISTN + h];
            uu[j] = *(const unsigned*)&histT[(size_t)item * 256 + c4];
        }
    }

    // tg factors for my 4 columns, pre-multiplied so Xs = 1024*X
    float tgs[4];
    if (c4 < 128) {
        float4 v = *(const float4*)&E_targ[(size_t)ti * 128 + c4];
        tgs[0] = v.x * 16.f; tgs[1] = v.y * 16.f;
        tgs[2] = v.z * 16.f; tgs[3] = v.w * 16.f;
    } else {
        // targ = [E_targ | Rout | Rin]; histT = [E_hist | Rin | Rout]
        int src = (c4 < 192) ? (c4 + 64) : (c4 - 64);
        unsigned u = *(const unsigned*)&histT[(size_t)ti * 256 + src];
        float f[4]; up_fp8x4(u, f);                 // = 64*tg
        tgs[0] = f[0] * 0.25f; tgs[1] = f[1] * 0.25f;
        tgs[2] = f[2] * 0.25f; tgs[3] = f[3] * 0.25f;
    }

    // ---- process + write X (fp8, scaled by 1024) ----
#pragma unroll
    for (int j = 0; j < 13; ++j) {
        if (hrow[j] < HISTN) {
            float f[4]; up_fp8x4(uu[j], f);
            *(unsigned*)&Xs[hrow[j]][c4] =
                pk_fp8x4(f[0] * tgs[0], f[1] * tgs[1], f[2] * tgs[2], f[3] * tgs[3]);
        }
    }
    __syncthreads();

    // ---- GEMM: H1 = X @ W1^T (fp8 MFMA); rowsum via B=ones ----
    floatx4 acc[4][2];
    floatx4 accr = (floatx4){0.f, 0.f, 0.f, 0.f};
#pragma unroll
    for (int m = 0; m < 4; ++m)
#pragma unroll
        for (int n = 0; n < 2; ++n) acc[m][n] = (floatx4){0.f, 0.f, 0.f, 0.f};

    const int ar = lane & 15;
    const int kb8 = (lane >> 4) << 3;
    const long* W1f = (const long*)W1s;
    const long ones = 0x3838383838383838L;          // fp8 e4m3 1.0 x8

#pragma unroll
    for (int k = 0; k < 8; ++k) {
        long a0 = *(const long*)&Xs[ar][k * 32 + kb8];
        long a1 = *(const long*)&Xs[16 + ar][k * 32 + kb8];
        long a2 = *(const long*)&Xs[32 + ar][k * 32 + kb8];
        long a3 = *(const long*)&Xs[48 + ar][k * 32 + kb8];
        long ax = *(const long*)&Xs[wv * 16 + ar][k * 32 + kb8];
        long bq0 = W1f[(k * 8 + nt0) * 64 + lane];
        long bq1 = W1f[(k * 8 + nt0 + 1) * 64 + lane];
        acc[0][0] = __builtin_amdgcn_mfma_f32_16x16x32_fp8_fp8(a0, bq0, acc[0][0], 0, 0, 0);
        acc[0][1] = __builtin_amdgcn_mfma_f32_16x16x32_fp8_fp8(a0, bq1, acc[0][1], 0, 0, 0);
        acc[1][0] = __builtin_amdgcn_mfma_f32_16x16x32_fp8_fp8(a1, bq0, acc[1][0], 0, 0, 0);
        acc[1][1] = __builtin_amdgcn_mfma_f32_16x16x32_fp8_fp8(a1, bq1, acc[1][1], 0, 0, 0);
        acc[2][0] = __builtin_amdgcn_mfma_f32_16x16x32_fp8_fp8(a2, bq0, acc[2][0], 0, 0, 0);
        acc[2][1] = __builtin_amdgcn_mfma_f32_16x16x32_fp8_fp8(a2, bq1, acc[2][1], 0, 0, 0);
        acc[3][0] = __builtin_amdgcn_mfma_f32_16x16x32_fp8_fp8(a3, bq0, acc[3][0], 0, 0, 0);
        acc[3][1] = __builtin_amdgcn_mfma_f32_16x16x32_fp8_fp8(a3, bq1, acc[3][1], 0, 0, 0);
        accr      = __builtin_amdgcn_mfma_f32_16x16x32_fp8_fp8(ax, ones, accr, 0, 0, 0);
    }

    if (ar == 0) {
        int hb = wv * 16 + ((lane >> 4) << 2);
        rowsumS[hb + 0] = accr[0] * INV_SX;
        rowsumS[hb + 1] = accr[1] * INV_SX;
        rowsumS[hb + 2] = accr[2] * INV_SX;
        rowsumS[hb + 3] = accr[3] * INV_SX;
    }

    float w2v[2], b1v[2];
#pragma unroll
    for (int n = 0; n < 2; ++n) {
        int o = (nt0 + n) * 16 + ar;
        w2v[n] = W2[o];
        b1v[n] = b1[o];
    }
#pragma unroll
    for (int m = 0; m < 4; ++m) {
        float p[4] = {0.f, 0.f, 0.f, 0.f};
#pragma unroll
        for (int n = 0; n < 2; ++n)
#pragma unroll
            for (int r = 0; r < 4; ++r)
                p[r] += w2v[n] * fmaxf(acc[m][n][r] * INV_SXSW + b1v[n], 0.f);
#pragma unroll
        for (int r = 0; r < 4; ++r) {
            float v = p[r];
            v += __shfl_xor(v, 1); v += __shfl_xor(v, 2);
            v += __shfl_xor(v, 4); v += __shfl_xor(v, 8);
            if (ar == 0) scoreP[wv][m * 16 + ((lane >> 4) << 2) + r] = v;
        }
    }
    __syncthreads();

    if (wv == 0) {
        float e = 0.f, er = 0.f;
        if (lane < HISTN) {
            int item = history[b * HISTN + lane];
            float sc = scoreP[0][lane] + scoreP[1][lane] + scoreP[2][lane] + scoreP[3][lane];
            e = (item != ti) ? expf(sc) : 0.f;
            er = e * rowsumS[lane];
        }
#pragma unroll
        for (int off = 1; off < 64; off <<= 1) {
            e += __shfl_xor(e, off);
            er += __shfl_xor(er, off);
        }
        if (lane == 0) {
            float pred = er / sqrtf(e);        // denom = (sum e)^0.5
            out[b] = 1.f / (1.f + expf(-pred));
        }
    }
}

extern "C" void kernel_launch(void* const* d_in, const int* in_sizes, int n_in,
                              void* d_out, int out_size, void* d_ws, size_t ws_size,
                              hipStream_t stream) {
    const int* history = (const int*)d_in[0];        // (4096,50)
    const int* target = (const int*)d_in[1];         // (4096,)
    const int* near_pois = (const int*)d_in[2];      // (50000,10)
    // d_in[3] = target_region: unused by reference
    const float* E_in = (const float*)d_in[4];       // (50000,64)
    const float* E_out = (const float*)d_in[5];      // (50000,64)
    const float* E_hist = (const float*)d_in[6];     // (50000,128)
    const float* E_targ = (const float*)d_in[7];     // (50000,128)
    const float* W1 = (const float*)d_in[8];         // (128,256)
    const float* b1 = (const float*)d_in[9];         // (128,)
    const float* W2 = (const float*)d_in[10];        // (1,128)
    float* out = (float*)d_out;                      // (4096,)

    unsigned char* W1s = (unsigned char*)d_ws;                   // 32 KB
    unsigned char* histT = W1s + 32768;                          // 12.8 MB fp8
    unsigned short* EioT = (unsigned short*)(histT + (size_t)ITEMN * 256); // 12.8 MB f16

    prep_eio<<<(ITEMN * 16) / 256, 256, 0, stream>>>(E_in, E_out, EioT);

    const int tailBlocks = (int)(((long)ITEMN * 16 + 4096 + 255) / 256);
    regions6<<<RBLK + tailBlocks, 256, 0, stream>>>(
        near_pois, EioT, E_hist, W1, histT, W1s);

    score_kernel<<<NBATCH, 256, 0, stream>>>(
        history, target, histT, E_targ, W1s, b1, W2, out);
}